// Round 4
// baseline (310.093 us; speedup 1.0000x reference)
//
#include <hip/hip_runtime.h>
#include <math.h>

#define DIM 160
#define NB 2
#define CHUNK 10
#define NCHZ (DIM / CHUNK)   // 16
#define NTHREADS 256
#define EPS_F 1.1920928955078125e-07f

// ws layout (doubles):
// [0..1] sum_mask[n], [2..3] sum_norm_pred[n], [4..5] sum_norm_tgt[n],
// [6] sum inner^2, [8..9] c_pred[n], [10..11] c_tgt[n]

__device__ __forceinline__ void srow(const float* __restrict__ p, int off,
                                     bool ok, bool xm, bool xp, float& S, float& D) {
  float f0 = ok ? p[off] : 0.f;
  float fm = (ok && xm) ? p[off - 1] : 0.f;
  float fp = (ok && xp) ? p[off + 1] : 0.f;
  S = fm + 2.f * f0 + fp;
  D = fp - fm;
}

// P1 = diff_x*smooth_y, P2 = smooth_x*diff_y, P3 = smooth_x*smooth_y at (x,y,z)
__device__ __forceinline__ void plane_P(const float* __restrict__ p, int off0,
                                        bool okm, bool ok0, bool okp, bool xm, bool xp,
                                        float& P1, float& P2, float& P3) {
  float Sm, Dm, S0, D0, Sp, Dp;
  srow(p, off0 - DIM, okm, xm, xp, Sm, Dm);
  srow(p, off0,       ok0, xm, xp, S0, D0);
  srow(p, off0 + DIM, okp, xm, xp, Sp, Dp);
  P1 = Dm + 2.f * D0 + Dp;
  P2 = Sp - Sm;
  P3 = Sm + 2.f * S0 + Sp;
}

__global__ __launch_bounds__(NTHREADS)
void pass1_kernel(const float* __restrict__ pred, const float* __restrict__ tgt,
                  const float* __restrict__ mask, double* __restrict__ ws) {
  __shared__ float red[3][4];
  const int tid = threadIdx.x;
  const int x = blockIdx.x * 32 + (tid & 31);
  const int y = blockIdx.y * 8 + (tid >> 5);
  const int n = blockIdx.z / NCHZ;
  const int zs = (blockIdx.z % NCHZ) * CHUNK;
  const size_t base = (size_t)n * DIM * DIM * DIM;
  const float* pb = pred + base;
  const float* tb = tgt + base;
  const float* mb = mask + base;

  const bool xm = (x >= 1), xp = (x <= DIM - 2);
  const bool ym = (y >= 1), yp = (y <= DIM - 2);

  float SL[2][3][3];  // [img][field][z-slot] — indices static after full unroll
  float am = 0.f, anp = 0.f, ant = 0.f;

#pragma unroll
  for (int i = 0; i < CHUNK + 2; ++i) {
    const int z = zs - 1 + i;
    const int c = i % 3, m1 = (i + 2) % 3, m2 = (i + 1) % 3;
    const bool zok = ((unsigned)z < DIM);
    const int off0 = (z * DIM + y) * DIM + x;
    plane_P(pb, off0, zok && ym, zok, zok && yp, xm, xp,
            SL[0][0][c], SL[0][1][c], SL[0][2][c]);
    plane_P(tb, off0, zok && ym, zok, zok && yp, xm, xp,
            SL[1][0][c], SL[1][1][c], SL[1][2][c]);
    if (i >= 2) {
      const int oidx = ((z - 1) * DIM + y) * DIM + x;
      const float m = mb[oidx];
      float gx0 = SL[0][0][m2] + 2.f * SL[0][0][m1] + SL[0][0][c];
      float gy0 = SL[0][1][m2] + 2.f * SL[0][1][m1] + SL[0][1][c];
      float gz0 = SL[0][2][c] - SL[0][2][m2];
      float gx1 = SL[1][0][m2] + 2.f * SL[1][0][m1] + SL[1][0][c];
      float gy1 = SL[1][1][m2] + 2.f * SL[1][1][m1] + SL[1][1][c];
      float gz1 = SL[1][2][c] - SL[1][2][m2];
      am += m;
      anp += sqrtf(gx0 * gx0 + gy0 * gy0 + gz0 * gz0 + EPS_F) * m;
      ant += sqrtf(gx1 * gx1 + gy1 * gy1 + gz1 * gz1 + EPS_F) * m;
    }
  }

  float v0 = am, v1 = anp, v2 = ant;
#pragma unroll
  for (int off = 32; off > 0; off >>= 1) {
    v0 += __shfl_down(v0, off, 64);
    v1 += __shfl_down(v1, off, 64);
    v2 += __shfl_down(v2, off, 64);
  }
  const int lane = tid & 63, wave = tid >> 6;
  if (lane == 0) { red[0][wave] = v0; red[1][wave] = v1; red[2][wave] = v2; }
  __syncthreads();
  if (tid == 0) {
    atomicAdd(&ws[0 + n], (double)(red[0][0] + red[0][1] + red[0][2] + red[0][3]));
    atomicAdd(&ws[2 + n], (double)(red[1][0] + red[1][1] + red[1][2] + red[1][3]));
    atomicAdd(&ws[4 + n], (double)(red[2][0] + red[2][1] + red[2][2] + red[2][3]));
  }
}

__global__ void compute_c_kernel(double* __restrict__ ws) {
  if (threadIdx.x == 0 && blockIdx.x == 0) {
    for (int n = 0; n < NB; ++n) {
      double inv_m = 1.0 / ws[0 + n];
      double ae_p = ws[2 + n] * inv_m;  // eta = 1.0
      double ae_t = ws[4 + n] * inv_m;
      ws[8 + n] = ae_p * ae_p + (double)EPS_F;
      ws[10 + n] = ae_t * ae_t + (double)EPS_F;
    }
  }
}

__global__ __launch_bounds__(NTHREADS)
void pass2_kernel(const float* __restrict__ pred, const float* __restrict__ tgt,
                  double* __restrict__ ws) {
  __shared__ float red[4];
  const int tid = threadIdx.x;
  const int x = blockIdx.x * 32 + (tid & 31);
  const int y = blockIdx.y * 8 + (tid >> 5);
  const int n = blockIdx.z / NCHZ;
  const int zs = (blockIdx.z % NCHZ) * CHUNK;
  const size_t base = (size_t)n * DIM * DIM * DIM;
  const float* pb = pred + base;
  const float* tb = tgt + base;

  const float cp = (float)ws[8 + n];
  const float ct = (float)ws[10 + n];

  const bool xm = (x >= 1), xp = (x <= DIM - 2);
  const bool ym = (y >= 1), yp = (y <= DIM - 2);

  float SL[2][3][3];
  float acc = 0.f;

#pragma unroll
  for (int i = 0; i < CHUNK + 2; ++i) {
    const int z = zs - 1 + i;
    const int c = i % 3, m1 = (i + 2) % 3, m2 = (i + 1) % 3;
    const bool zok = ((unsigned)z < DIM);
    const int off0 = (z * DIM + y) * DIM + x;
    plane_P(pb, off0, zok && ym, zok, zok && yp, xm, xp,
            SL[0][0][c], SL[0][1][c], SL[0][2][c]);
    plane_P(tb, off0, zok && ym, zok, zok && yp, xm, xp,
            SL[1][0][c], SL[1][1][c], SL[1][2][c]);
    if (i >= 2) {
      float gpx = SL[0][0][m2] + 2.f * SL[0][0][m1] + SL[0][0][c];
      float gpy = SL[0][1][m2] + 2.f * SL[0][1][m1] + SL[0][1][c];
      float gpz = SL[0][2][c] - SL[0][2][m2];
      float gtx = SL[1][0][m2] + 2.f * SL[1][0][m1] + SL[1][0][c];
      float gty = SL[1][1][m2] + 2.f * SL[1][1][m1] + SL[1][1][c];
      float gtz = SL[1][2][c] - SL[1][2][m2];
      float sqp = gpx * gpx + gpy * gpy + gpz * gpz;
      float sqt = gtx * gtx + gty * gty + gtz * gtz;
      float dot = gpx * gtx + gpy * gty + gpz * gtz;
      float inner = dot * rsqrtf((sqp + cp) * (sqt + ct));
      acc += inner * inner;
    }
  }

#pragma unroll
  for (int off = 32; off > 0; off >>= 1) acc += __shfl_down(acc, off, 64);
  const int lane = tid & 63, wave = tid >> 6;
  if (lane == 0) red[wave] = acc;
  __syncthreads();
  if (tid == 0) atomicAdd(&ws[6], (double)(red[0] + red[1] + red[2] + red[3]));
}

__global__ void finalize_kernel(const double* __restrict__ ws, float* __restrict__ out) {
  if (threadIdx.x == 0 && blockIdx.x == 0) {
    double mean = ws[6] / ((double)NB * DIM * DIM * DIM);
    out[0] = (float)(1.0 - mean);
  }
}

extern "C" void kernel_launch(void* const* d_in, const int* in_sizes, int n_in,
                              void* d_out, int out_size, void* d_ws, size_t ws_size,
                              hipStream_t stream) {
  const float* pred = (const float*)d_in[0];
  const float* tgt = (const float*)d_in[1];
  const float* mask = (const float*)d_in[2];
  float* out = (float*)d_out;
  double* ws = (double*)d_ws;

  hipMemsetAsync(d_ws, 0, 16 * sizeof(double), stream);

  dim3 grid(DIM / 32, DIM / 8, NCHZ * NB);  // 5 x 20 x 32 = 3200 blocks
  pass1_kernel<<<grid, NTHREADS, 0, stream>>>(pred, tgt, mask, ws);
  compute_c_kernel<<<1, 64, 0, stream>>>(ws);
  pass2_kernel<<<grid, NTHREADS, 0, stream>>>(pred, tgt, ws);
  finalize_kernel<<<1, 64, 0, stream>>>(ws, out);
}

// Round 5
// 152.167 us; speedup vs baseline: 2.0378x; 2.0378x over previous
//
#include <hip/hip_runtime.h>
#include <math.h>

#define DIM 160
#define NB 2
#define CHUNK 5
#define NCHZ (DIM / CHUNK)   // 32
#define NTHREADS 256
#define EPS_F 1.1920928955078125e-07f

// ws layout (doubles):
// [0..1] sum_mask[n], [2..3] sum_norm_pred[n], [4..5] sum_norm_tgt[n],
// [6] sum inner^2, [8..9] c_pred[n], [10..11] c_tgt[n]

__device__ __forceinline__ float4 ldv(const float* __restrict__ p, bool ok) {
  float4 r = make_float4(0.f, 0.f, 0.f, 0.f);
  if (ok) r = *(const float4*)p;
  return r;
}

// P1 = diff_x*smooth_y, P2 = smooth_x*diff_y, P3 = smooth_x*smooth_y for 4 voxels
// at (xb..xb+3, y, z). 9 independent aligned float4 loads, zero-padded at edges.
__device__ __forceinline__ void plane_P(const float* __restrict__ img, int off0,
                                        bool zok, bool ym, bool yp, bool xl, bool xr,
                                        float (&P1)[4], float (&P2)[4], float (&P3)[4]) {
#pragma unroll
  for (int r = 0; r < 3; ++r) {
    const bool rv = zok && (r == 0 ? ym : (r == 2 ? yp : true));
    const int offr = off0 + (r - 1) * DIM;
    float4 L = ldv(img + offr - 4, rv && xl);
    float4 M = ldv(img + offr, rv);
    float4 R = ldv(img + offr + 4, rv && xr);
    float fm1 = L.w, f0 = M.x, f1 = M.y, f2 = M.z, f3 = M.w, f4 = R.x;
    float S[4], D[4];
    S[0] = fm1 + 2.f * f0 + f1;  D[0] = f1 - fm1;
    S[1] = f0 + 2.f * f1 + f2;   D[1] = f2 - f0;
    S[2] = f1 + 2.f * f2 + f3;   D[2] = f3 - f1;
    S[3] = f2 + 2.f * f3 + f4;   D[3] = f4 - f2;
    if (r == 0) {
#pragma unroll
      for (int j = 0; j < 4; ++j) { P1[j] = D[j]; P2[j] = -S[j]; P3[j] = S[j]; }
    } else if (r == 1) {
#pragma unroll
      for (int j = 0; j < 4; ++j) { P1[j] += 2.f * D[j]; P3[j] += 2.f * S[j]; }
    } else {
#pragma unroll
      for (int j = 0; j < 4; ++j) { P1[j] += D[j]; P2[j] += S[j]; P3[j] += S[j]; }
    }
  }
}

// One image per block (im = 0 pred, 1 tgt). Pending-output scheme:
// processing plane z finalizes out[z-1], updates out[z], initializes out[z+1].
__global__ __launch_bounds__(NTHREADS)
void pass1_kernel(const float* __restrict__ pred, const float* __restrict__ tgt,
                  const float* __restrict__ mask, double* __restrict__ ws) {
  __shared__ float red[2][4];
  const int tid = threadIdx.x;
  const int tx = tid & 7, ty = tid >> 3;
  int bz = blockIdx.z;
  const int im = bz & 1; bz >>= 1;
  const int n = bz / NCHZ;
  const int zs = (bz % NCHZ) * CHUNK;
  const int xb = blockIdx.x * 32 + tx * 4;
  const int y = blockIdx.y * 32 + ty;
  const size_t base = (size_t)n * DIM * DIM * DIM;
  const float* img = (im == 0 ? pred : tgt) + base;
  const float* mb = mask + base;

  const bool xl = (xb >= 4), xr = (xb + 4 < DIM);
  const bool ym = (y >= 1), yp = (y <= DIM - 2);

  float OUT[2][3][4];
#pragma unroll
  for (int s = 0; s < 2; ++s)
#pragma unroll
    for (int f = 0; f < 3; ++f)
#pragma unroll
      for (int j = 0; j < 4; ++j) OUT[s][f][j] = 0.f;

  float am = 0.f, an = 0.f;

#pragma unroll
  for (int i = 0; i < CHUNK + 2; ++i) {
    const int z = zs - 1 + i;
    const bool zok = ((unsigned)z < DIM);
    const int off0 = (z * DIM + y) * DIM + xb;
    float P1[4], P2[4], P3[4];
    plane_P(img, off0, zok, ym, yp, xl, xr, P1, P2, P3);
    const int sA = i & 1, sB = sA ^ 1;
    if (i >= 2) {
      const int zo = z - 1;
      if (im == 0) {
        const float4 mv = *(const float4*)(mb + (zo * DIM + y) * DIM + xb);
        const float m4[4] = {mv.x, mv.y, mv.z, mv.w};
#pragma unroll
        for (int j = 0; j < 4; ++j) {
          float gx = OUT[sA][0][j] + P1[j];
          float gy = OUT[sA][1][j] + P2[j];
          float gz = OUT[sA][2][j] + P3[j];
          am += m4[j];
          an += sqrtf(gx * gx + gy * gy + gz * gz + EPS_F) * m4[j];
        }
      } else {
#pragma unroll
        for (int j = 0; j < 4; ++j) {
          float gx = OUT[sA][0][j] + P1[j];
          float gy = OUT[sA][1][j] + P2[j];
          float gz = OUT[sA][2][j] + P3[j];
          an += sqrtf(gx * gx + gy * gy + gz * gz + EPS_F);
        }
      }
    }
#pragma unroll
    for (int j = 0; j < 4; ++j) {
      OUT[sA][0][j] = P1[j];
      OUT[sA][1][j] = P2[j];
      OUT[sA][2][j] = -P3[j];
      OUT[sB][0][j] += 2.f * P1[j];
      OUT[sB][1][j] += 2.f * P2[j];
    }
  }

  float v0 = am, v1 = an;
#pragma unroll
  for (int off = 32; off > 0; off >>= 1) {
    v0 += __shfl_down(v0, off, 64);
    v1 += __shfl_down(v1, off, 64);
  }
  const int lane = tid & 63, wave = tid >> 6;
  if (lane == 0) { red[0][wave] = v0; red[1][wave] = v1; }
  __syncthreads();
  if (tid == 0) {
    if (im == 0) atomicAdd(&ws[0 + n], (double)(red[0][0] + red[0][1] + red[0][2] + red[0][3]));
    atomicAdd(&ws[2 + 2 * im + n], (double)(red[1][0] + red[1][1] + red[1][2] + red[1][3]));
  }
}

__global__ void compute_c_kernel(double* __restrict__ ws) {
  if (threadIdx.x == 0 && blockIdx.x == 0) {
    for (int n = 0; n < NB; ++n) {
      double inv_m = 1.0 / ws[0 + n];
      double ae_p = ws[2 + n] * inv_m;  // eta = 1.0
      double ae_t = ws[4 + n] * inv_m;
      ws[8 + n] = ae_p * ae_p + (double)EPS_F;
      ws[10 + n] = ae_t * ae_t + (double)EPS_F;
    }
  }
}

__global__ __launch_bounds__(NTHREADS)
void pass2_kernel(const float* __restrict__ pred, const float* __restrict__ tgt,
                  double* __restrict__ ws) {
  __shared__ float red[4];
  const int tid = threadIdx.x;
  const int tx = tid & 7, ty = tid >> 3;
  const int bz = blockIdx.z;
  const int n = bz / NCHZ;
  const int zs = (bz % NCHZ) * CHUNK;
  const int xb = blockIdx.x * 32 + tx * 4;
  const int y = blockIdx.y * 32 + ty;
  const size_t base = (size_t)n * DIM * DIM * DIM;
  const float* pb = pred + base;
  const float* tb = tgt + base;

  const float cp = (float)ws[8 + n];
  const float ct = (float)ws[10 + n];

  const bool xl = (xb >= 4), xr = (xb + 4 < DIM);
  const bool ym = (y >= 1), yp = (y <= DIM - 2);

  float OUT[2][2][3][4];  // [slot][img][field][j]
#pragma unroll
  for (int s = 0; s < 2; ++s)
#pragma unroll
    for (int g = 0; g < 2; ++g)
#pragma unroll
      for (int f = 0; f < 3; ++f)
#pragma unroll
        for (int j = 0; j < 4; ++j) OUT[s][g][f][j] = 0.f;

  float acc = 0.f;

#pragma unroll
  for (int i = 0; i < CHUNK + 2; ++i) {
    const int z = zs - 1 + i;
    const bool zok = ((unsigned)z < DIM);
    const int off0 = (z * DIM + y) * DIM + xb;
    float P[2][3][4];
    plane_P(pb, off0, zok, ym, yp, xl, xr, P[0][0], P[0][1], P[0][2]);
    plane_P(tb, off0, zok, ym, yp, xl, xr, P[1][0], P[1][1], P[1][2]);
    const int sA = i & 1, sB = sA ^ 1;
    if (i >= 2) {
#pragma unroll
      for (int j = 0; j < 4; ++j) {
        float gpx = OUT[sA][0][0][j] + P[0][0][j];
        float gpy = OUT[sA][0][1][j] + P[0][1][j];
        float gpz = OUT[sA][0][2][j] + P[0][2][j];
        float gtx = OUT[sA][1][0][j] + P[1][0][j];
        float gty = OUT[sA][1][1][j] + P[1][1][j];
        float gtz = OUT[sA][1][2][j] + P[1][2][j];
        float sqp = gpx * gpx + gpy * gpy + gpz * gpz;
        float sqt = gtx * gtx + gty * gty + gtz * gtz;
        float dot = gpx * gtx + gpy * gty + gpz * gtz;
        float inner = dot * rsqrtf((sqp + cp) * (sqt + ct));
        acc += inner * inner;
      }
    }
#pragma unroll
    for (int g = 0; g < 2; ++g)
#pragma unroll
      for (int j = 0; j < 4; ++j) {
        OUT[sA][g][0][j] = P[g][0][j];
        OUT[sA][g][1][j] = P[g][1][j];
        OUT[sA][g][2][j] = -P[g][2][j];
        OUT[sB][g][0][j] += 2.f * P[g][0][j];
        OUT[sB][g][1][j] += 2.f * P[g][1][j];
      }
  }

#pragma unroll
  for (int off = 32; off > 0; off >>= 1) acc += __shfl_down(acc, off, 64);
  const int lane = tid & 63, wave = tid >> 6;
  if (lane == 0) red[wave] = acc;
  __syncthreads();
  if (tid == 0) atomicAdd(&ws[6], (double)(red[0] + red[1] + red[2] + red[3]));
}

__global__ void finalize_kernel(const double* __restrict__ ws, float* __restrict__ out) {
  if (threadIdx.x == 0 && blockIdx.x == 0) {
    double mean = ws[6] / ((double)NB * DIM * DIM * DIM);
    out[0] = (float)(1.0 - mean);
  }
}

extern "C" void kernel_launch(void* const* d_in, const int* in_sizes, int n_in,
                              void* d_out, int out_size, void* d_ws, size_t ws_size,
                              hipStream_t stream) {
  const float* pred = (const float*)d_in[0];
  const float* tgt = (const float*)d_in[1];
  const float* mask = (const float*)d_in[2];
  float* out = (float*)d_out;
  double* ws = (double*)d_ws;

  hipMemsetAsync(d_ws, 0, 16 * sizeof(double), stream);

  dim3 grid1(DIM / 32, DIM / 32, NCHZ * NB * 2);  // 5 x 5 x 128 = 3200 blocks
  pass1_kernel<<<grid1, NTHREADS, 0, stream>>>(pred, tgt, mask, ws);
  compute_c_kernel<<<1, 64, 0, stream>>>(ws);
  dim3 grid2(DIM / 32, DIM / 32, NCHZ * NB);      // 5 x 5 x 64 = 1600 blocks
  pass2_kernel<<<grid2, NTHREADS, 0, stream>>>(pred, tgt, ws);
  finalize_kernel<<<1, 64, 0, stream>>>(ws, out);
}